// Round 4
// baseline (303.524 us; speedup 1.0000x reference)
//
#include <hip/hip_runtime.h>
#include <hip/hip_cooperative_groups.h>

namespace cg = cooperative_groups;

// Problem constants
#define B 4
#define S 8192
#define D 256
#define H 8
#define NT 128               // tiles per batch, 64 rows each
#define LOG2E 1.4426950408889634f

// Workspace layout (float offsets)
#define WS_WQ    0
#define WS_WV    8
#define WS_QMAX  16
#define WS_QMIN  (WS_QMAX + B*D)        // 1040
#define WS_CV    (WS_QMIN + B*D)        // 2064
#define WS_KC    (WS_CV + B*D)          // 3088
#define WS_WP    (WS_KC + B*H*D)        // 11280
#define WS_P1    (WS_WP + 1024)         // 12304
#define WS_P2    (WS_P1 + B*NT*D)
#define WS_P3    (WS_P2 + B*NT*D)
#define WS_PZ    (WS_P3 + B*NT*D)       // + B*NT*H*D -> ~5.8 MB total

__global__ __launch_bounds__(256, 2) void fused(const float* __restrict__ q,
                                                const float* __restrict__ v,
                                                const float* __restrict__ qw,
                                                const float* __restrict__ vw,
                                                float* __restrict__ ws,
                                                float* __restrict__ out) {
    cg::grid_group grid = cg::this_grid();
    __shared__ float tile[64 * 256];          // 64 KB: this block's q rows, swizzled

    const int blk = blockIdx.x;               // 512 blocks = (b, tl)
    const int b = blk >> 7, tl = blk & 127;
    const int t = threadIdx.x;
    const int w = t >> 6, lane = t & 63;

    // ================= Phase A =================
    // A1: weight-chunk partials (blocks 0..255; blk>>7 selects qw/vw)
    if (blk < 256) {
        const int h = (blk >> 4) & 7, ch = blk & 15;
        const float4* src = (const float4*)(((blk >> 7) ? vw : qw)
                                            + (size_t)h * D * D + ch * 4096);
        float sm = 0.f;
        #pragma unroll
        for (int j = 0; j < 4; ++j) {
            float4 a4 = src[j * 256 + t];
            sm += (a4.x + a4.y) + (a4.z + a4.w);
        }
        #pragma unroll
        for (int off = 32; off; off >>= 1) sm += __shfl_down(sm, off, 64);
        if (lane == 0) ws[WS_WP + blk * 4 + w] = sm;
    }

    // A2: stage q tile into LDS (swizzled) + col max/min of q + col sum of v.
    // Wave w owns cols [w*64, w*64+64); lane: g = row-subgroup, cl = col-block.
    {
        const int g = lane >> 4, cl = lane & 15;
        const int cblk = w * 16 + cl;                    // 16B col block, 0..63
        const float4* qbase = (const float4*)(q + ((size_t)b * S + tl * 64) * D);
        const float4* vbase = (const float4*)(v + ((size_t)b * S + tl * 64) * D);
        float4 qmx = make_float4(-3.4e38f, -3.4e38f, -3.4e38f, -3.4e38f);
        float4 qmn = make_float4(3.4e38f, 3.4e38f, 3.4e38f, 3.4e38f);
        float4 vs = make_float4(0.f, 0.f, 0.f, 0.f);
        #pragma unroll 4
        for (int i = 0; i < 16; ++i) {
            const int row = i * 4 + g;
            float4 a4 = qbase[row * 64 + cblk];
            qmx.x = fmaxf(qmx.x, a4.x); qmx.y = fmaxf(qmx.y, a4.y);
            qmx.z = fmaxf(qmx.z, a4.z); qmx.w = fmaxf(qmx.w, a4.w);
            qmn.x = fminf(qmn.x, a4.x); qmn.y = fminf(qmn.y, a4.y);
            qmn.z = fminf(qmn.z, a4.z); qmn.w = fminf(qmn.w, a4.w);
            *(float4*)&tile[row * 256 + (cblk ^ (row & 7)) * 4] = a4;
            float4 b4 = vbase[row * 64 + cblk];
            vs.x += b4.x; vs.y += b4.y; vs.z += b4.z; vs.w += b4.w;
        }
        #pragma unroll
        for (int off = 16; off <= 32; off <<= 1) {
            qmx.x = fmaxf(qmx.x, __shfl_xor(qmx.x, off, 64));
            qmx.y = fmaxf(qmx.y, __shfl_xor(qmx.y, off, 64));
            qmx.z = fmaxf(qmx.z, __shfl_xor(qmx.z, off, 64));
            qmx.w = fmaxf(qmx.w, __shfl_xor(qmx.w, off, 64));
            qmn.x = fminf(qmn.x, __shfl_xor(qmn.x, off, 64));
            qmn.y = fminf(qmn.y, __shfl_xor(qmn.y, off, 64));
            qmn.z = fminf(qmn.z, __shfl_xor(qmn.z, off, 64));
            qmn.w = fminf(qmn.w, __shfl_xor(qmn.w, off, 64));
            vs.x += __shfl_xor(vs.x, off, 64);
            vs.y += __shfl_xor(vs.y, off, 64);
            vs.z += __shfl_xor(vs.z, off, 64);
            vs.w += __shfl_xor(vs.w, off, 64);
        }
        if (g == 0) {
            size_t pi = (size_t)(b * NT + tl) * D + cblk * 4;
            *(float4*)&ws[WS_P1 + pi] = qmx;
            *(float4*)&ws[WS_P2 + pi] = qmn;
            *(float4*)&ws[WS_P3 + pi] = vs;
        }
    }
    grid.sync();

    // ================= Phase B1: finish col stats + weight sums =================
    if (blk < 32) {
        const int bb = blk >> 3, oct = blk & 7;
        const int dl = t >> 3, sub = t & 7;
        const int d = oct * 32 + dl;
        float mx = -3.4e38f, mn = 3.4e38f, sm = 0.f;
        #pragma unroll 4
        for (int i = 0; i < 16; ++i) {
            size_t idx = (size_t)(bb * NT + sub * 16 + i) * D + d;
            mx = fmaxf(mx, ws[WS_P1 + idx]);
            mn = fminf(mn, ws[WS_P2 + idx]);
            sm += ws[WS_P3 + idx];
        }
        #pragma unroll
        for (int off = 1; off < 8; off <<= 1) {
            mx = fmaxf(mx, __shfl_xor(mx, off, 64));
            mn = fminf(mn, __shfl_xor(mn, off, 64));
            sm += __shfl_xor(sm, off, 64);
        }
        if (sub == 0) {
            ws[WS_QMAX + bb * D + d] = mx;
            ws[WS_QMIN + bb * D + d] = mn;
            ws[WS_CV + bb * D + d] = sm * (float)D;
        }
    } else if (blk == 32) {
        const int o = t >> 4, j = t & 15;        // o: 0..15 = (which,h)
        float s = 0.f;
        #pragma unroll
        for (int ww = 0; ww < 4; ++ww) s += ws[WS_WP + (o * 16 + j) * 4 + ww];
        #pragma unroll
        for (int off = 1; off < 16; off <<= 1) s += __shfl_xor(s, off, 64);
        if (j == 0) ws[(o >= 8) ? (WS_WV + o - 8) : (WS_WQ + o)] = s;
    }
    grid.sync();

    // ================= Phase B2: Z partials over this block's 64 rows =================
    {
        const int d = t;
        const float qmxv = ws[WS_QMAX + b * D + d];
        const float qmnv = ws[WS_QMIN + b * D + d];
        float a[H], cc[H], z[H];
        #pragma unroll
        for (int h = 0; h < H; ++h) {
            float wq_ = ws[WS_WQ + h];
            float M = (wq_ >= 0.f) ? wq_ * qmxv : wq_ * qmnv;
            a[h] = wq_ * LOG2E;
            cc[h] = -M * LOG2E;
            z[h] = 0.f;
        }
        const int c = d >> 2, comp = d & 3;
        #pragma unroll 4
        for (int r = 0; r < 64; ++r) {
            float qv = tile[r * 256 + (c ^ (r & 7)) * 4 + comp];
            #pragma unroll
            for (int h = 0; h < H; ++h) z[h] += exp2f(fmaf(qv, a[h], cc[h]));
        }
        const size_t base = (size_t)(b * NT + tl) * H * D;
        #pragma unroll
        for (int h = 0; h < H; ++h) ws[WS_PZ + base + h * D + d] = z[h];
    }
    grid.sync();

    // ================= Phase B3: reduce Z -> kc =================
    if (blk < 64) {
        const int bb = blk >> 4, seg = blk & 15;
        const int h = t >> 5, dl = (t >> 1) & 15, sub = t & 1;
        const int d = seg * 16 + dl;
        float z = 0.f;
        #pragma unroll 8
        for (int i = 0; i < 64; ++i) {
            z += ws[WS_PZ + ((size_t)(bb * NT + sub * 64 + i) * H + h) * D + d];
        }
        z += __shfl_xor(z, 1, 64);
        if (sub == 0) {
            float wq_ = ws[WS_WQ + h];
            float M = (wq_ >= 0.f) ? wq_ * ws[WS_QMAX + bb * D + d]
                                   : wq_ * ws[WS_QMIN + bb * D + d];
            ws[WS_KC + (bb * H + h) * D + d] = -M * LOG2E - log2f(z);
        }
    }
    grid.sync();

    // ================= Phase C: final output for this block's 64 rows =================
    {
        const int rl = lane >> 2, slice = lane & 3;   // 4 lanes per row
        const int row = w * 16 + rl;
        float a[H], wv_[H], p[H];
        #pragma unroll
        for (int h = 0; h < H; ++h) {
            a[h] = ws[WS_WQ + h] * LOG2E;
            wv_[h] = ws[WS_WV + h];
            p[h] = 0.f;
        }
        const float* kcb = ws + WS_KC + b * H * D;
        for (int j = 0; j < 16; ++j) {
            const int c = slice * 16 + j;
            float4 qv = *(float4*)&tile[row * 256 + (c ^ (row & 7)) * 4];
            #pragma unroll
            for (int h = 0; h < H; ++h) {
                float4 k4 = *(const float4*)&kcb[h * D + c * 4];
                p[h] += (exp2f(fmaf(qv.x, a[h], k4.x)) + exp2f(fmaf(qv.y, a[h], k4.y)))
                      + (exp2f(fmaf(qv.z, a[h], k4.z)) + exp2f(fmaf(qv.w, a[h], k4.w)));
            }
        }
        #pragma unroll
        for (int off = 1; off <= 2; off <<= 1) {
            #pragma unroll
            for (int h = 0; h < H; ++h) p[h] += __shfl_xor(p[h], off, 64);
        }
        float amax = -3.4e38f, amin = 3.4e38f;
        #pragma unroll
        for (int h = 0; h < H; ++h) {
            float A = wv_[h] * p[h];
            amax = fmaxf(amax, A);
            amin = fminf(amin, A);
        }
        float4 cvp = *(const float4*)&ws[WS_CV + b * D + lane * 4];
        float* obase = out + ((size_t)b * S + tl * 64 + w * 16) * D;
        #pragma unroll
        for (int rr = 0; rr < 16; ++rr) {
            float am = __shfl(amax, rr * 4, 64);
            float an = __shfl(amin, rr * 4, 64);
            float4 o;
            o.x = (cvp.x >= 0.f) ? cvp.x * am : cvp.x * an;
            o.y = (cvp.y >= 0.f) ? cvp.y * am : cvp.y * an;
            o.z = (cvp.z >= 0.f) ? cvp.z * am : cvp.z * an;
            o.w = (cvp.w >= 0.f) ? cvp.w * am : cvp.w * an;
            *(float4*)&obase[rr * 256 + lane * 4] = o;     // 1KB contiguous per wave-inst
        }
    }
}

// ---------------------------------------------------------------------------
extern "C" void kernel_launch(void* const* d_in, const int* in_sizes, int n_in,
                              void* d_out, int out_size, void* d_ws, size_t ws_size,
                              hipStream_t stream) {
    const float* q  = (const float*)d_in[0];
    // d_in[1] (k) and d_in[4] (k_weights) are provably unused: softmax over s sums to 1.
    const float* v  = (const float*)d_in[2];
    const float* qw = (const float*)d_in[3];
    const float* vw = (const float*)d_in[5];
    float* out = (float*)d_out;
    float* ws  = (float*)d_ws;

    void* kargs[] = {(void*)&q, (void*)&v, (void*)&qw, (void*)&vw,
                     (void*)&ws, (void*)&out};
    hipLaunchCooperativeKernel((const void*)fused, dim3(B * NT), dim3(256),
                               kargs, 0, stream);
}

// Round 5
// 70.233 us; speedup vs baseline: 4.3217x; 4.3217x over previous
//
#include <hip/hip_runtime.h>

// Problem constants
#define B 4
#define S 8192
#define D 256
#define H 8
#define NT 128               // col-stat tiles per batch, 64 rows each
#define LOG2E 1.4426950408889634f

// Workspace layout (float offsets)
#define WS_WQ    0
#define WS_WV    8
#define WS_QMAX  16
#define WS_QMIN  (WS_QMAX + B*D)
#define WS_CV    (WS_QMIN + B*D)
#define WS_ZACC  (WS_CV + B*D)          // B*H*D = 8192 accumulators
#define WS_WP    (WS_ZACC + B*H*D)      // 1024 weight partials
#define WS_P1    (WS_WP + 1024)
#define WS_P2    (WS_P1 + B*NT*D)
#define WS_P3    (WS_P2 + B*NT*D)

// ---------------------------------------------------------------------------
// kA: blocks [0,512): per-tile col stats of q (max/min) and v (sum).
//     blocks [512,768): weight-chunk partial sums.
__global__ __launch_bounds__(256) void kA(const float* __restrict__ q,
                                          const float* __restrict__ v,
                                          const float* __restrict__ qw,
                                          const float* __restrict__ vw,
                                          float* __restrict__ ws) {
    const int blk = blockIdx.x;
    const int t = threadIdx.x, w = t >> 6, lane = t & 63;

    if (blk >= B * NT) {                       // weight partials
        const int i = blk - B * NT;            // 0..255: which=i>>7, h=(i>>4)&7, ch=i&15
        const float4* src = (const float4*)(((i >> 7) ? vw : qw)
                              + (size_t)((i >> 4) & 7) * D * D) + (i & 15) * 1024;
        float sm = 0.f;
        #pragma unroll
        for (int j = 0; j < 4; ++j) {
            float4 a4 = src[j * 256 + t];
            sm += (a4.x + a4.y) + (a4.z + a4.w);
        }
        #pragma unroll
        for (int off = 32; off; off >>= 1) sm += __shfl_down(sm, off, 64);
        if (lane == 0) ws[WS_WP + i * 4 + w] = sm;
        return;
    }

    const int b = blk >> 7, tl = blk & (NT - 1);
    const int g = lane >> 4, cl = lane & 15;
    const int cblk = w * 16 + cl;              // 16B col block, 0..63
    const float4* qbase = (const float4*)(q + ((size_t)b * S + tl * 64) * D);
    const float4* vbase = (const float4*)(v + ((size_t)b * S + tl * 64) * D);
    float4 qmx = make_float4(-3.4e38f, -3.4e38f, -3.4e38f, -3.4e38f);
    float4 qmn = make_float4(3.4e38f, 3.4e38f, 3.4e38f, 3.4e38f);
    float4 vs = make_float4(0.f, 0.f, 0.f, 0.f);
    #pragma unroll 4
    for (int i = 0; i < 16; ++i) {
        const int row = i * 4 + g;
        float4 a4 = qbase[row * 64 + cblk];
        qmx.x = fmaxf(qmx.x, a4.x); qmx.y = fmaxf(qmx.y, a4.y);
        qmx.z = fmaxf(qmx.z, a4.z); qmx.w = fmaxf(qmx.w, a4.w);
        qmn.x = fminf(qmn.x, a4.x); qmn.y = fminf(qmn.y, a4.y);
        qmn.z = fminf(qmn.z, a4.z); qmn.w = fminf(qmn.w, a4.w);
        float4 b4 = vbase[row * 64 + cblk];
        vs.x += b4.x; vs.y += b4.y; vs.z += b4.z; vs.w += b4.w;
    }
    #pragma unroll
    for (int off = 16; off <= 32; off <<= 1) {
        qmx.x = fmaxf(qmx.x, __shfl_xor(qmx.x, off, 64));
        qmx.y = fmaxf(qmx.y, __shfl_xor(qmx.y, off, 64));
        qmx.z = fmaxf(qmx.z, __shfl_xor(qmx.z, off, 64));
        qmx.w = fmaxf(qmx.w, __shfl_xor(qmx.w, off, 64));
        qmn.x = fminf(qmn.x, __shfl_xor(qmn.x, off, 64));
        qmn.y = fminf(qmn.y, __shfl_xor(qmn.y, off, 64));
        qmn.z = fminf(qmn.z, __shfl_xor(qmn.z, off, 64));
        qmn.w = fminf(qmn.w, __shfl_xor(qmn.w, off, 64));
        vs.x += __shfl_xor(vs.x, off, 64);
        vs.y += __shfl_xor(vs.y, off, 64);
        vs.z += __shfl_xor(vs.z, off, 64);
        vs.w += __shfl_xor(vs.w, off, 64);
    }
    if (g == 0) {
        size_t pi = (size_t)(b * NT + tl) * D + cblk * 4;
        *(float4*)&ws[WS_P1 + pi] = qmx;
        *(float4*)&ws[WS_P2 + pi] = qmn;
        *(float4*)&ws[WS_P3 + pi] = vs;
    }
}

// ---------------------------------------------------------------------------
// kB: blocks 0..31 finish col stats; block 32 finishes weight sums;
//     block 33 zeroes the Z accumulators.
__global__ __launch_bounds__(256) void kB(float* __restrict__ ws) {
    const int blk = blockIdx.x, t = threadIdx.x;
    if (blk < 32) {
        const int bb = blk >> 3, oct = blk & 7;
        const int dl = t >> 3, sub = t & 7;
        const int d = oct * 32 + dl;
        float mx = -3.4e38f, mn = 3.4e38f, sm = 0.f;
        #pragma unroll 4
        for (int i = 0; i < 16; ++i) {
            size_t idx = (size_t)(bb * NT + sub * 16 + i) * D + d;
            mx = fmaxf(mx, ws[WS_P1 + idx]);
            mn = fminf(mn, ws[WS_P2 + idx]);
            sm += ws[WS_P3 + idx];
        }
        #pragma unroll
        for (int off = 1; off < 8; off <<= 1) {
            mx = fmaxf(mx, __shfl_xor(mx, off, 64));
            mn = fminf(mn, __shfl_xor(mn, off, 64));
            sm += __shfl_xor(sm, off, 64);
        }
        if (sub == 0) {
            ws[WS_QMAX + bb * D + d] = mx;
            ws[WS_QMIN + bb * D + d] = mn;
            ws[WS_CV + bb * D + d] = sm * (float)D;
        }
    } else if (blk == 32) {
        const int o = t >> 4, j = t & 15;        // o: 0..15 = (which,h)
        float s = 0.f;
        #pragma unroll
        for (int ww = 0; ww < 4; ++ww) s += ws[WS_WP + (o * 16 + j) * 4 + ww];
        #pragma unroll
        for (int off = 1; off < 16; off <<= 1) s += __shfl_xor(s, off, 64);
        if (j == 0) ws[(o >= 8) ? (WS_WV + o - 8) : (WS_WQ + o)] = s;
    } else {
        #pragma unroll
        for (int e = 0; e < 8; ++e)
            *(float4*)&ws[WS_ZACC + e * 1024 + t * 4] = make_float4(0.f, 0.f, 0.f, 0.f);
    }
}

// ---------------------------------------------------------------------------
// kC: Z partials over 32-row chunks, accumulated with atomicAdd into WS_ZACC.
__global__ __launch_bounds__(256) void kC(const float* __restrict__ q,
                                          float* __restrict__ ws) {
    const int blk = blockIdx.x;          // 1024 blocks: b = blk>>8, chunk = blk&255
    const int b = blk >> 8, c = blk & 255;
    const int d = threadIdx.x;
    const float qmx = ws[WS_QMAX + b * D + d];
    const float qmn = ws[WS_QMIN + b * D + d];
    float a[H], cc[H], z[H];
    #pragma unroll
    for (int h = 0; h < H; ++h) {
        float wq_ = ws[WS_WQ + h];
        float M = (wq_ >= 0.f) ? wq_ * qmx : wq_ * qmn;  // max_s of wq*q[b,s,d]
        a[h] = wq_ * LOG2E;
        cc[h] = -M * LOG2E;
        z[h] = 0.f;
    }
    const float* qp = q + ((size_t)b * S + c * 32) * D + d;
    #pragma unroll 4
    for (int r = 0; r < 32; ++r) {
        float qv = qp[(size_t)r * D];
        #pragma unroll
        for (int h = 0; h < H; ++h) z[h] += exp2f(fmaf(qv, a[h], cc[h]));
    }
    #pragma unroll
    for (int h = 0; h < H; ++h)
        atomicAdd(&ws[WS_ZACC + (b * H + h) * D + d], z[h]);
}

// ---------------------------------------------------------------------------
// kE: per block (64 rows): recompute kc into LDS, then per-row Qs via 16-lane
//     slices + shfl reduce; stores are full-wave 1KB-contiguous per row.
#define SUM4(Q, H_, J) \
    ((exp2f(fmaf((Q).x, a[H_], kc[H_][J].x)) + exp2f(fmaf((Q).y, a[H_], kc[H_][J].y))) + \
     (exp2f(fmaf((Q).z, a[H_], kc[H_][J].z)) + exp2f(fmaf((Q).w, a[H_], kc[H_][J].w))))

__global__ __launch_bounds__(256, 2) void kE(const float* __restrict__ q,
                                             const float* __restrict__ ws,
                                             float* __restrict__ out) {
    __shared__ float kcs[H * D];
    const int blk = blockIdx.x;
    const int b = blk >> 7, tl = blk & (NT - 1);
    const int t = threadIdx.x, w = t >> 6, lane = t & 63;

    // prologue: kc[h,d] = -M*log2e - log2(Z)
    #pragma unroll
    for (int e = 0; e < 8; ++e) {
        int idx = e * 256 + t;
        int h = idx >> 8, d = idx & 255;
        float wq_ = ws[WS_WQ + h];
        float M = (wq_ >= 0.f) ? wq_ * ws[WS_QMAX + b * D + d]
                               : wq_ * ws[WS_QMIN + b * D + d];
        kcs[idx] = -M * LOG2E - log2f(ws[WS_ZACC + (b * H + h) * D + d]);
    }
    __syncthreads();

    const int g = lane >> 4, sl = lane & 15;   // g: row in group-of-4, sl: 16-col slice
    float a[H], wv_[H];
    float4 kc[H][4];
    #pragma unroll
    for (int h = 0; h < H; ++h) {
        a[h] = ws[WS_WQ + h] * LOG2E;
        wv_[h] = ws[WS_WV + h];
        #pragma unroll
        for (int j = 0; j < 4; ++j)
            kc[h][j] = *(float4*)&kcs[h * 256 + sl * 16 + j * 4];
    }
    float4 cvs = *(const float4*)&ws[WS_CV + b * D + lane * 4];

    const float* qrow = q + ((size_t)b * S + tl * 64 + w * 16) * D;
    float* orow = out + ((size_t)b * S + tl * 64 + w * 16) * D;

    #pragma unroll
    for (int it = 0; it < 4; ++it) {
        const float4* qp = (const float4*)(qrow + (it * 4 + g) * D + sl * 16);
        float4 q0 = qp[0], q1 = qp[1], q2 = qp[2], q3 = qp[3];
        float p[H];
        #pragma unroll
        for (int h = 0; h < H; ++h)
            p[h] = (SUM4(q0, h, 0) + SUM4(q1, h, 1)) + (SUM4(q2, h, 2) + SUM4(q3, h, 3));
        #pragma unroll
        for (int st = 1; st < 16; st <<= 1) {
            #pragma unroll
            for (int h = 0; h < H; ++h) p[h] += __shfl_xor(p[h], st, 16);
        }
        float amax = -3.4e38f, amin = 3.4e38f;
        #pragma unroll
        for (int h = 0; h < H; ++h) {
            float A = wv_[h] * p[h];
            amax = fmaxf(amax, A);
            amin = fminf(amin, A);
        }
        #pragma unroll
        for (int rr = 0; rr < 4; ++rr) {
            float am = __shfl(amax, rr * 16, 64);
            float an = __shfl(amin, rr * 16, 64);
            float4 o;
            o.x = (cvs.x >= 0.f) ? cvs.x * am : cvs.x * an;
            o.y = (cvs.y >= 0.f) ? cvs.y * am : cvs.y * an;
            o.z = (cvs.z >= 0.f) ? cvs.z * am : cvs.z * an;
            o.w = (cvs.w >= 0.f) ? cvs.w * am : cvs.w * an;
            *(float4*)&orow[(it * 4 + rr) * D + lane * 4] = o;   // 1KB/wave contiguous
        }
    }
}

// ---------------------------------------------------------------------------
extern "C" void kernel_launch(void* const* d_in, const int* in_sizes, int n_in,
                              void* d_out, int out_size, void* d_ws, size_t ws_size,
                              hipStream_t stream) {
    const float* q  = (const float*)d_in[0];
    // d_in[1] (k) and d_in[4] (k_weights) are provably unused: softmax over s sums to 1.
    const float* v  = (const float*)d_in[2];
    const float* qw = (const float*)d_in[3];
    const float* vw = (const float*)d_in[5];
    float* out = (float*)d_out;
    float* ws  = (float*)d_ws;

    kA<<<B * NT + 256, 256, 0, stream>>>(q, v, qw, vw, ws);
    kB<<<34, 256, 0, stream>>>(ws);
    kC<<<1024, 256, 0, stream>>>(q, ws);
    kE<<<B * NT, 256, 0, stream>>>(q, ws, out);
}